// Round 1
// baseline (90.778 us; speedup 1.0000x reference)
//
#include <hip/hip_runtime.h>
#include <math.h>

// Problem constants (from reference setup_inputs): B=256, K=51, N=8192
#define NPTS      8192
#define KDIM      51
#define KPAD      64
#define BATCH     256
#define CHUNKS    64            // n-chunks per d
#define CHUNK_N   128           // NPTS / CHUNKS
#define LDSTRIDE  68            // padded row stride (floats) for bs staging
#define MULT      0.0025f

// ---------------------------------------------------------------------------
// Kernel 1: per-(d, n-chunk) partial Gram matrix G_d[k1,k2] = sum_n bs[k1,n,d]*bs[k2,n,d]
// Grid: 3*CHUNKS blocks, 256 threads. Each lane owns an 8x8 tile of the 64x64
// (zero-padded) Gram; waves split the 128-n chunk 32 n's each; cross-wave
// reduce through a swizzled LDS region; one 4096-float partial per block.
// ---------------------------------------------------------------------------
__global__ __launch_bounds__(256) void pl_gram_partial(
    const float* __restrict__ bs, float* __restrict__ partial) {
    __shared__ float lds[8704];          // max(128*68 staging, 2*4096 reduce)

    const int bx  = blockIdx.x;
    const int d   = bx / CHUNKS;
    const int n0  = (bx % CHUNKS) * CHUNK_N;
    const int tid = threadIdx.x;

    // Stage bs[k][n0+n][d] -> lds[n*68 + k], zero-pad k in [51,64)
    for (int idx = tid; idx < CHUNK_N * KPAD; idx += 256) {
        int n = idx & (CHUNK_N - 1);
        int k = idx >> 7;
        float v = 0.0f;
        if (k < KDIM) v = bs[k * (NPTS * 3) + (n0 + n) * 3 + d];
        lds[n * LDSTRIDE + k] = v;
    }
    __syncthreads();

    const int wave = tid >> 6;
    const int lane = tid & 63;
    const int g1   = lane >> 3;   // a-group (rows k1 = g1*8..+7)
    const int g2   = lane & 7;    // b-group (cols k2 = g2*8..+7)

    float acc[8][8];
#pragma unroll
    for (int i = 0; i < 8; ++i)
#pragma unroll
        for (int j = 0; j < 8; ++j) acc[i][j] = 0.0f;

    const int nb = wave * 32;
    for (int n = nb; n < nb + 32; ++n) {
        const float* row = &lds[n * LDSTRIDE];
        float4 t0 = *reinterpret_cast<const float4*>(row + (g1 << 3));
        float4 t1 = *reinterpret_cast<const float4*>(row + (g1 << 3) + 4);
        float4 u0 = *reinterpret_cast<const float4*>(row + (g2 << 3));
        float4 u1 = *reinterpret_cast<const float4*>(row + (g2 << 3) + 4);
        float a[8] = {t0.x, t0.y, t0.z, t0.w, t1.x, t1.y, t1.z, t1.w};
        float b[8] = {u0.x, u0.y, u0.z, u0.w, u1.x, u1.y, u1.z, u1.w};
#pragma unroll
        for (int i = 0; i < 8; ++i)
#pragma unroll
            for (int j = 0; j < 8; ++j)
                acc[i][j] = fmaf(a[i], b[j], acc[i][j]);
    }

    // Cross-wave reduce: waves 2,3 write slots {0,1}; waves 0,1 add into them.
    // Swizzled layout slot[w][lane][ (idx+lane)&63 ] -> conflict-free.
    __syncthreads();   // staging reads done before overwrite
    if (wave >= 2) {
#pragma unroll
        for (int idx = 0; idx < 64; ++idx)
            lds[(wave - 2) * 4096 + lane * 64 + ((idx + lane) & 63)] =
                acc[idx >> 3][idx & 7];
    }
    __syncthreads();
    if (wave < 2) {
#pragma unroll
        for (int idx = 0; idx < 64; ++idx)
            lds[wave * 4096 + lane * 64 + ((idx + lane) & 63)] +=
                acc[idx >> 3][idx & 7];
    }
    __syncthreads();

    // Emit 4096-float block partial: entry e = owner_lane*64 + (i*8+j)
    for (int e = tid; e < 4096; e += 256) {
        int l = e >> 6, r = e & 63;
        int sw = l * 64 + ((r + l) & 63);
        partial[(size_t)bx * 4096 + e] = lds[sw] + lds[4096 + sw];
    }
}

// ---------------------------------------------------------------------------
// Kernel 2: reduce chunk partials -> G[3][4096]; also zero d_out.
// Grid: 48 blocks x 256 threads (3*4096 entries).
// ---------------------------------------------------------------------------
__global__ __launch_bounds__(256) void pl_reduce_gram(
    const float* __restrict__ partial, float* __restrict__ G,
    float* __restrict__ out) {
    int e = blockIdx.x * 256 + threadIdx.x;      // [0, 3*4096)
    int d = e >> 12, el = e & 4095;
    float s = 0.0f;
    for (int c = 0; c < CHUNKS; ++c)
        s += partial[(size_t)(d * CHUNKS + c) * 4096 + el];
    G[e] = s;
    if (e == 0) out[0] = 0.0f;
}

// ---------------------------------------------------------------------------
// Kernel 3: quadratic forms + sqrt + global sum.
// Grid: 48 blocks = 3 d x 16 b-groups of 16. 256 threads = (b_local, j) 16x16.
// ---------------------------------------------------------------------------
__global__ __launch_bounds__(256) void pl_finalize(
    const float* __restrict__ G, const float* __restrict__ yh,
    const float* __restrict__ yv, float* __restrict__ out) {
    __shared__ float Gl[64 * 65];    // padded stride 65: bank-safe
    __shared__ float wl[16 * 52];
    __shared__ float red2[16];

    const int bx  = blockIdx.x;
    const int d   = bx / 16;
    const int b0  = (bx % 16) * 16;
    const int tid = threadIdx.x;

    // Load G[d] (tile-scattered layout) -> Gl[k1][k2]
    for (int idx = tid; idx < 4096; idx += 256) {
        float v = G[d * 4096 + idx];
        int l = idx >> 6, r = idx & 63;
        int k1 = ((l >> 3) << 3) | (r >> 3);
        int k2 = ((l & 7) << 3) | (r & 7);
        Gl[k1 * 65 + k2] = v;
    }
    // w = y_hat - y for this block's 16 batch rows
    for (int idx = tid; idx < 16 * KDIM; idx += 256) {
        int bl = idx / KDIM, k = idx % KDIM;
        int gi = (b0 + bl) * KDIM + k;
        wl[bl * 52 + k] = yh[gi] - yv[gi];
    }
    __syncthreads();

    const int bl = tid >> 4;     // batch-local row
    const int j  = tid & 15;     // k1 strip
    float pq = 0.0f;
    for (int k1 = j; k1 < KDIM; k1 += 16) {
        float t = 0.0f;
        const float* gr = &Gl[k1 * 65];
        const float* wr = &wl[bl * 52];
#pragma unroll
        for (int k2 = 0; k2 < KDIM; ++k2) t = fmaf(gr[k2], wr[k2], t);
        pq = fmaf(wl[bl * 52 + k1], t, pq);
    }
    // reduce over the 16-lane j-strip
    for (int off = 8; off; off >>= 1) pq += __shfl_down(pq, off, 16);
    if (j == 0) red2[bl] = sqrtf(pq);
    __syncthreads();
    if (tid == 0) {
        float s = 0.0f;
#pragma unroll
        for (int i = 0; i < 16; ++i) s += red2[i];
        atomicAdd(out, s * MULT);
    }
}

extern "C" void kernel_launch(void* const* d_in, const int* in_sizes, int n_in,
                              void* d_out, int out_size, void* d_ws, size_t ws_size,
                              hipStream_t stream) {
    const float* y_hat = (const float*)d_in[0];   // [256,51]
    const float* y     = (const float*)d_in[1];   // [256,51]
    // d_in[2] = face [8192,3] — cancels algebraically, unused
    const float* bs    = (const float*)d_in[3];   // [51,8192,3]
    float* out = (float*)d_out;

    float* partial = (float*)d_ws;                        // 192*4096 floats
    float* G       = partial + (size_t)3 * CHUNKS * 4096; // 3*4096 floats

    pl_gram_partial<<<3 * CHUNKS, 256, 0, stream>>>(bs, partial);
    pl_reduce_gram<<<48, 256, 0, stream>>>(partial, G, out);
    pl_finalize<<<48, 256, 0, stream>>>(G, y_hat, y, out);
}

// Round 2
// 80.930 us; speedup vs baseline: 1.1217x; 1.1217x over previous
//
#include <hip/hip_runtime.h>
#include <math.h>

// B=256, K=51, N=8192. out = MULT * sum_{b,d} sqrt(w_b^T G_d w_b),
// w = y_hat - y, G_d[k1,k2] = sum_n bs[k1,n,d]*bs[k2,n,d].
// (face cancels; EPS cross-term ~1e-6 relative -> dropped, validated round 1.)
#define NPTS     8192
#define KDIM     51
#define KPAD     64
#define CHUNKS   64
#define CHUNK_N  128
#define MULT     0.0025f

typedef short short8  __attribute__((ext_vector_type(8)));
typedef float float4v __attribute__((ext_vector_type(4)));

// RNE f32 -> bf16 bits (inputs are normal floats; NaN path irrelevant)
__device__ __forceinline__ unsigned short f32_to_bf16(float f) {
    unsigned int u = __float_as_uint(f);
    unsigned int r = u + 0x7FFFu + ((u >> 16) & 1u);
    return (unsigned short)(r >> 16);
}

// ---------------------------------------------------------------------------
// Kernel 1: per-(d, 128-point chunk) partial Gram via MFMA bf16.
// LDS: lds16[shape][point], stride 136 bf16 (=68 dwords; 68%32=4 -> rows
// rotate banks, staged pair-writes are 2-way = free). Each of 4 waves owns a
// 32x32 quadrant as 2x2 16x16 tiles; K-loop 4 iters of K=32 points.
// mfma_f32_16x16x32_bf16 layouts (HW-verified, guide §3):
//   A: m=lane&15, k=(lane>>4)*8+j  (8 contiguous points)   B: mirror
//   C: col=lane&15, row=(lane>>4)*4+reg
// G symmetric => robust to A/B role mixups; only k-mapping must match (it does).
// ---------------------------------------------------------------------------
__global__ __launch_bounds__(256) void pl_gram(
    const float* __restrict__ bs, float* __restrict__ partial) {
  __shared__ unsigned short lds16[KPAD * 136];

  const int bx  = blockIdx.x;
  const int d   = bx / CHUNKS;
  const int n0  = (bx % CHUNKS) * CHUNK_N;
  const int tid = threadIdx.x;

  // Stage: u -> (shape k = u>>6, point-pair np = u&63). Lanes: np consecutive,
  // k fixed -> LDS banks (4k+np)%32 = all 32, 2-way (free). Global: stride-24B
  // lanes; sibling d-blocks (bx±64, same XCD for %8 swizzle) reuse the lines.
  unsigned int* lds32 = (unsigned int*)lds16;
  for (int u = tid; u < KPAD * (CHUNK_N / 2); u += 256) {
    int np = u & 63;
    int k  = u >> 6;
    float v0 = 0.0f, v1 = 0.0f;
    if (k < KDIM) {
      const float* p = bs + (size_t)k * (NPTS * 3) + (size_t)(n0 + 2 * np) * 3 + d;
      v0 = p[0];
      v1 = p[3];
    }
    lds32[k * 68 + np] = (unsigned int)f32_to_bf16(v0) |
                         ((unsigned int)f32_to_bf16(v1) << 16);
  }
  __syncthreads();

  const int wave  = tid >> 6;
  const int lane  = tid & 63;
  const int m16   = lane & 15;
  const int quad  = lane >> 4;
  const int rbase = (wave >> 1) * 32;
  const int cbase = (wave & 1) * 32;

  float4v acc00 = {0.f, 0.f, 0.f, 0.f}, acc01 = {0.f, 0.f, 0.f, 0.f};
  float4v acc10 = {0.f, 0.f, 0.f, 0.f}, acc11 = {0.f, 0.f, 0.f, 0.f};

#pragma unroll
  for (int p0 = 0; p0 < CHUNK_N; p0 += 32) {
    const int po = p0 + quad * 8;
    short8 a0 = *(const short8*)&lds16[(rbase +      m16) * 136 + po];
    short8 a1 = *(const short8*)&lds16[(rbase + 16 + m16) * 136 + po];
    short8 b0 = *(const short8*)&lds16[(cbase +      m16) * 136 + po];
    short8 b1 = *(const short8*)&lds16[(cbase + 16 + m16) * 136 + po];
    acc00 = __builtin_amdgcn_mfma_f32_16x16x32_bf16(a0, b0, acc00, 0, 0, 0);
    acc01 = __builtin_amdgcn_mfma_f32_16x16x32_bf16(a0, b1, acc01, 0, 0, 0);
    acc10 = __builtin_amdgcn_mfma_f32_16x16x32_bf16(a1, b0, acc10, 0, 0, 0);
    acc11 = __builtin_amdgcn_mfma_f32_16x16x32_bf16(a1, b1, acc11, 0, 0, 0);
  }

  // Emit in NATURAL [row][col] layout (k3 unscramble gone). Shapes >=51 are
  // zero-padded -> rows/cols >=51 hold exact zeros (valid to reduce).
  float* pout = partial + (size_t)bx * 4096;
#pragma unroll
  for (int r = 0; r < 4; ++r) {
    int row0 = rbase + quad * 4 + r;
    int col0 = cbase + m16;
    pout[row0 * 64 + col0]             = acc00[r];
    pout[row0 * 64 + (col0 + 16)]      = acc01[r];
    pout[(row0 + 16) * 64 + col0]      = acc10[r];
    pout[(row0 + 16) * 64 + (col0 + 16)] = acc11[r];
  }
}

// ---------------------------------------------------------------------------
// Kernel 2: reduce 64 chunk partials -> G[3][4096]; zero d_out for kernel 3.
// ---------------------------------------------------------------------------
__global__ __launch_bounds__(256) void pl_reduce_gram(
    const float* __restrict__ partial, float* __restrict__ G,
    float* __restrict__ out) {
  int e = blockIdx.x * 256 + threadIdx.x;   // [0, 3*4096)
  int d = e >> 12, el = e & 4095;
  float s = 0.0f;
  for (int c = 0; c < CHUNKS; ++c)
    s += partial[(size_t)(d * CHUNKS + c) * 4096 + el];
  G[e] = s;
  if (e == 0) out[0] = 0.0f;
}

// ---------------------------------------------------------------------------
// Kernel 3: q[b,d] = w_b^T G_d w_b, out += MULT * sum sqrt(q).
// 48 blocks = 3 d x 16 groups of 16 batch rows; 256 thr = (row, j-strip 16).
// ---------------------------------------------------------------------------
__global__ __launch_bounds__(256) void pl_finalize(
    const float* __restrict__ G, const float* __restrict__ yh,
    const float* __restrict__ yv, float* __restrict__ out) {
  __shared__ float Gl[64 * 65];   // stride 65: bank-safe rows
  __shared__ float wl[16 * 52];
  __shared__ float red2[16];

  const int bx  = blockIdx.x;
  const int d   = bx >> 4;
  const int b0  = (bx & 15) << 4;
  const int tid = threadIdx.x;

  for (int idx = tid; idx < 4096; idx += 256)
    Gl[(idx >> 6) * 65 + (idx & 63)] = G[d * 4096 + idx];
  for (int idx = tid; idx < 16 * KDIM; idx += 256) {
    int bl = idx / KDIM, k = idx - bl * KDIM;
    int gi = (b0 + bl) * KDIM + k;
    wl[bl * 52 + k] = yh[gi] - yv[gi];
  }
  __syncthreads();

  const int bl = tid >> 4;
  const int j  = tid & 15;
  float pq = 0.0f;
  for (int k1 = j; k1 < KDIM; k1 += 16) {
    float t = 0.0f;
    const float* gr = &Gl[k1 * 65];
    const float* wr = &wl[bl * 52];
#pragma unroll
    for (int k2 = 0; k2 < KDIM; ++k2) t = fmaf(gr[k2], wr[k2], t);
    pq = fmaf(wl[bl * 52 + k1], t, pq);
  }
  for (int off = 8; off; off >>= 1) pq += __shfl_down(pq, off, 16);
  if (j == 0) red2[bl] = sqrtf(pq);
  __syncthreads();
  if (tid == 0) {
    float s = 0.0f;
#pragma unroll
    for (int i = 0; i < 16; ++i) s += red2[i];
    atomicAdd(out, s * MULT);
  }
}

extern "C" void kernel_launch(void* const* d_in, const int* in_sizes, int n_in,
                              void* d_out, int out_size, void* d_ws, size_t ws_size,
                              hipStream_t stream) {
  const float* y_hat = (const float*)d_in[0];   // [256,51]
  const float* y     = (const float*)d_in[1];   // [256,51]
  // d_in[2] = face [8192,3] — cancels algebraically, unused
  const float* bs    = (const float*)d_in[3];   // [51,8192,3]
  float* out = (float*)d_out;

  float* partial = (float*)d_ws;                          // 192*4096 floats
  float* G       = partial + (size_t)3 * CHUNKS * 4096;   // 3*4096 floats

  pl_gram<<<3 * CHUNKS, 256, 0, stream>>>(bs, partial);
  pl_reduce_gram<<<48, 256, 0, stream>>>(partial, G, out);
  pl_finalize<<<48, 256, 0, stream>>>(G, y_hat, y, out);
}